// Round 6
// baseline (313.469 us; speedup 1.0000x reference)
//
#include <hip/hip_runtime.h>
#include <cmath>

#define D_MODEL 512
#define N_HEADS 8
#define HEAD_DIM 64
#define D_FF 2048
#define SEQ 2048
#define BATCH 2
#define MROWS (BATCH * SEQ) /* 4096 */

typedef __attribute__((ext_vector_type(8))) short short8;
typedef __attribute__((ext_vector_type(4))) float float4v;
typedef unsigned short ushort_t;

static __device__ __forceinline__ ushort_t f2bf(float f) {
    union { float f; unsigned u; } v; v.f = f;
    unsigned r = (v.u + 0x7FFFu + ((v.u >> 16) & 1u)) >> 16;
    return (ushort_t)r;
}
static __device__ __forceinline__ ushort_t f2bf_trunc(float f) {
    union { float f; unsigned u; } v; v.f = f;
    return (ushort_t)(v.u >> 16);
}

// ---------------------------------------------------------------------------
// prep: weight transpose/convert (tiles 0..3071) + x fp32->bf16 (3072..5119)
// ---------------------------------------------------------------------------
__global__ __launch_bounds__(256) void prep_k(
    const float* __restrict__ x,
    const float* __restrict__ Wq, const float* __restrict__ Wk,
    const float* __restrict__ Wv, const float* __restrict__ Wo,
    const float* __restrict__ W1, const float* __restrict__ W2,
    ushort_t* __restrict__ xb,
    ushort_t* __restrict__ WqkvT, ushort_t* __restrict__ WoT,
    ushort_t* __restrict__ W1T, ushort_t* __restrict__ W2T)
{
    int tile = blockIdx.x;
    if (tile >= 3072) {                    // x -> bf16
        int i = (tile - 3072) * 256 + threadIdx.x;
        float4 f = ((const float4*)x)[i];
        ushort4 o;
        o.x = f2bf(f.x); o.y = f2bf(f.y); o.z = f2bf(f.z); o.w = f2bf(f.w);
        ((ushort4*)xb)[i] = o;
        return;
    }
    const float* src; ushort_t* dst; int Kd, Nd, tloc;
    if (tile < 1024) {
        int wsel = tile >> 8; tloc = tile & 255; Kd = 512; Nd = 512;
        if (wsel == 0)      { src = Wq; dst = WqkvT; }
        else if (wsel == 1) { src = Wk; dst = WqkvT + (size_t)512 * 512; }
        else if (wsel == 2) { src = Wv; dst = WqkvT + (size_t)1024 * 512; }
        else                { src = Wo; dst = WoT; }
    } else if (tile < 2048) { tloc = tile - 1024; Kd = 512;  Nd = 2048; src = W1; dst = W1T; }
    else                    { tloc = tile - 2048; Kd = 2048; Nd = 512;  src = W2; dst = W2T; }
    int tn = Nd >> 5;
    int k0 = (tloc / tn) << 5, n0 = (tloc % tn) << 5;
    __shared__ float tl[32][33];
    int c = threadIdx.x & 31, r = threadIdx.x >> 5;
    #pragma unroll
    for (int i = 0; i < 4; ++i)
        tl[r + i * 8][c] = src[(size_t)(k0 + r + i * 8) * Nd + n0 + c];
    __syncthreads();
    #pragma unroll
    for (int i = 0; i < 4; ++i)
        dst[(size_t)(n0 + r + i * 8) * Kd + k0 + c] = f2bf(tl[c][r + i * 8]);
}

// ---------------------------------------------------------------------------
// Direct-load MFMA GEMM (no LDS, no barriers). Block 256 thr = 4 independent
// waves, each owning a 32x64 tile (wave n-offset = w*64, block covers 256 n).
// Register double-buffer: load k+32 fragments while MFMA-ing k.
// MODE: 0 = fp32+bias; 1 = bf16+bias+ReLU; 2 = fp32 raw split-K partial.
// ---------------------------------------------------------------------------
#define DL_LOAD(buf, koff)                                                     \
    {                                                                          \
        _Pragma("unroll")                                                      \
        for (int mt = 0; mt < 2; ++mt)                                         \
            af[buf][mt] = *(const short8*)(Ap + (size_t)mt * 16 * K + (koff)); \
        _Pragma("unroll")                                                      \
        for (int nt = 0; nt < 4; ++nt)                                         \
            bf8[buf][nt] = *(const short8*)(Bp + (size_t)nt * 16 * K + (koff));\
    }
#define DL_MFMA(buf)                                                           \
    {                                                                          \
        _Pragma("unroll")                                                      \
        for (int mt = 0; mt < 2; ++mt)                                         \
            _Pragma("unroll")                                                  \
            for (int nt = 0; nt < 4; ++nt)                                     \
                acc[mt][nt] = __builtin_amdgcn_mfma_f32_16x16x32_bf16(         \
                    af[buf][mt], bf8[buf][nt], acc[mt][nt], 0, 0, 0);          \
    }

template <int MODE>
__global__ __launch_bounds__(256) void gemm_dl_k(
    const ushort_t* __restrict__ A, const ushort_t* __restrict__ BT,
    const float* __restrict__ bias, void* __restrict__ Cv,
    int N, int K, int Klen, size_t zstride)
{
    const int t = threadIdx.x;
    const int w = t >> 6, lane = t & 63, l16 = lane & 15, quad = lane >> 4;
    const int m0 = blockIdx.y * 32;
    const int n0 = blockIdx.x * 256 + w * 64;
    const int kbase = blockIdx.z * Klen;

    const ushort_t* Ap = A + (size_t)(m0 + l16) * K + kbase + quad * 8;
    const ushort_t* Bp = BT + (size_t)(n0 + l16) * K + kbase + quad * 8;

    float4v acc[2][4];
    #pragma unroll
    for (int mt = 0; mt < 2; ++mt)
        #pragma unroll
        for (int nt = 0; nt < 4; ++nt)
            acc[mt][nt] = (float4v){0.f, 0.f, 0.f, 0.f};

    short8 af[2][2], bf8[2][4];
    DL_LOAD(0, 0)
    const int nsteps = Klen >> 6;
    for (int kk = 0; kk < nsteps; ++kk) {
        const int k = kk << 6;
        DL_LOAD(1, k + 32)
        DL_MFMA(0)
        if (kk + 1 < nsteps) DL_LOAD(0, k + 64)
        DL_MFMA(1)
    }

    float* Cf = (float*)Cv + blockIdx.z * zstride;
    #pragma unroll
    for (int mt = 0; mt < 2; ++mt) {
        #pragma unroll
        for (int nt = 0; nt < 4; ++nt) {
            int gcol = n0 + nt * 16 + l16;
            float b = (MODE == 2) ? 0.f : bias[gcol];
            #pragma unroll
            for (int r = 0; r < 4; ++r) {
                int grow = m0 + mt * 16 + quad * 4 + r;
                float v = acc[mt][nt][r] + b;
                if (MODE == 1) v = fmaxf(v, 0.f);
                if (MODE == 1) ((ushort_t*)Cv)[(size_t)grow * N + gcol] = f2bf(v);
                else           Cf[(size_t)grow * N + gcol] = v;
            }
        }
    }
}

// ---------------------------------------------------------------------------
// Direct-load fused QKV GEMM: A[4096,512] @ WqkvT[1536,512]^T.
// Wave-uniform epilogue select (each wave's 64-col span within one of Q/K/V).
// Q scale folds 1/sqrt(64) and log2(e).
// ---------------------------------------------------------------------------
__global__ __launch_bounds__(256) void gemm_dl_qkv(
    const ushort_t* __restrict__ A, const ushort_t* __restrict__ BT,
    const float* __restrict__ bq, const float* __restrict__ bk,
    const float* __restrict__ bv,
    ushort_t* __restrict__ Qb, ushort_t* __restrict__ Kb,
    ushort_t* __restrict__ VTb)
{
    const int t = threadIdx.x;
    const int w = t >> 6, lane = t & 63, l16 = lane & 15, quad = lane >> 4;
    const int m0 = blockIdx.y * 32;
    const int n0 = blockIdx.x * 256 + w * 64;
    const int K = 512;

    const ushort_t* Ap = A + (size_t)(m0 + l16) * K + quad * 8;
    const ushort_t* Bp = BT + (size_t)(n0 + l16) * K + quad * 8;

    float4v acc[2][4];
    #pragma unroll
    for (int mt = 0; mt < 2; ++mt)
        #pragma unroll
        for (int nt = 0; nt < 4; ++nt)
            acc[mt][nt] = (float4v){0.f, 0.f, 0.f, 0.f};

    short8 af[2][2], bf8[2][4];
    DL_LOAD(0, 0)
    for (int kk = 0; kk < 8; ++kk) {
        const int k = kk << 6;
        DL_LOAD(1, k + 32)
        DL_MFMA(0)
        if (kk + 1 < 8) DL_LOAD(0, k + 64)
        DL_MFMA(1)
    }

    const int tsel = n0 >> 9;                       // 0=Q 1=K 2=V (wave-uniform)
    const float* bias = (tsel == 0) ? bq : (tsel == 1) ? bk : bv;
    const float scl = (tsel == 0) ? 0.18033688f : 1.0f;  // 0.125 * log2(e)
    ushort_t* dst = (tsel == 0) ? Qb : Kb;

    #pragma unroll
    for (int mt = 0; mt < 2; ++mt) {
        #pragma unroll
        for (int nt = 0; nt < 4; ++nt) {
            int gcol = n0 + nt * 16 + l16;
            int lcol = gcol - (tsel << 9);
            int h = lcol >> 6, dh = lcol & 63;
            float b = bias[lcol];
            #pragma unroll
            for (int r = 0; r < 4; ++r) {
                int grow = m0 + mt * 16 + quad * 4 + r;
                int bb = grow >> 11, s = grow & 2047;
                float v = (acc[mt][nt][r] + b) * scl;
                if (tsel < 2)
                    dst[(((size_t)(bb * N_HEADS + h)) * SEQ + s) * HEAD_DIM + dh] = f2bf(v);
                else
                    VTb[(((size_t)(bb * N_HEADS + h)) * HEAD_DIM + dh) * SEQ + s] = f2bf(v);
            }
        }
    }
}

// ---------------------------------------------------------------------------
// bf16 MFMA flash attention: fixed-max exp2 softmax, split-K x4.
// Grid (16 bh, 32 qt, 4 ks). LDS 26.6 KB -> 6 blocks/CU.
// Ps: stride 64 with XOR-swizzled 16B chunks (conflict-free reads+writes).
// ---------------------------------------------------------------------------
__global__ __launch_bounds__(256) void attn_mfma_k(
    const ushort_t* __restrict__ Qg, const ushort_t* __restrict__ Kg,
    const ushort_t* __restrict__ VTg,
    float* __restrict__ Opart, float* __restrict__ Lpart)
{
    __shared__ __align__(16) ushort_t Ks[64 * 72];
    __shared__ __align__(16) ushort_t Vs[64 * 72];
    __shared__ __align__(16) ushort_t Ps[4][16 * 64];   // swizzled

    const int bh = blockIdx.x;
    const int q0 = blockIdx.y * 64;
    const int ks = blockIdx.z;
    const int t = threadIdx.x;
    const int w = t >> 6;
    const int lane = t & 63;
    const int l16 = lane & 15;
    const int quad = lane >> 4;
    const int qbase = q0 + w * 16;
    const float M2 = 14.4269504f;   // 10*log2(e); scores pre-scaled by log2(e)/8

    short8 aq[2];
    {
        const ushort_t* qp = Qg + ((size_t)bh * SEQ + qbase + l16) * HEAD_DIM + quad * 8;
        aq[0] = *(const short8*)(qp);
        aq[1] = *(const short8*)(qp + 32);
    }

    float4v o[4] = {};
    float l_acc[4] = {0.f, 0.f, 0.f, 0.f};

    for (int kt = 0; kt < 8; ++kt) {
        const int kbase = ks * 512 + kt * 64;
        __syncthreads();
        #pragma unroll
        for (int lit = 0; lit < 2; ++lit) {
            int flat = lit * 256 + t;
            int row = flat >> 3;
            int c0 = (flat & 7) * 8;
            *(short8*)&Ks[row * 72 + c0] =
                *(const short8*)(Kg + ((size_t)bh * SEQ + kbase + row) * HEAD_DIM + c0);
            *(short8*)&Vs[row * 72 + c0] =
                *(const short8*)(VTg + ((size_t)bh * HEAD_DIM + row) * SEQ + kbase + c0);
        }
        __syncthreads();

        float4v s[4];
        #pragma unroll
        for (int nt = 0; nt < 4; ++nt) s[nt] = (float4v){0.f, 0.f, 0.f, 0.f};
        #pragma unroll
        for (int c = 0; c < 2; ++c) {
            #pragma unroll
            for (int nt = 0; nt < 4; ++nt) {
                short8 bk8 = *(const short8*)&Ks[(nt * 16 + l16) * 72 + c * 32 + quad * 8];
                s[nt] = __builtin_amdgcn_mfma_f32_16x16x32_bf16(aq[c], bk8, s[nt], 0, 0, 0);
            }
        }

        #pragma unroll
        for (int nt = 0; nt < 4; ++nt) {
            #pragma unroll
            for (int r = 0; r < 4; ++r) {
                float p = exp2f(s[nt][r] - M2);
                s[nt][r] = p;
                l_acc[r] += p;
            }
        }

        // P -> per-wave LDS, swizzled: elem(row,key) at row*64 + ((key>>3)^(row&7))*8 + (key&7)
        #pragma unroll
        for (int nt = 0; nt < 4; ++nt)
            #pragma unroll
            for (int r = 0; r < 4; ++r) {
                int row = quad * 4 + r;
                int key = nt * 16 + l16;
                Ps[w][row * 64 + (((key >> 3) ^ (row & 7)) << 3) + (key & 7)] =
                    f2bf_trunc(s[nt][r]);
            }
        asm volatile("s_waitcnt lgkmcnt(0)" ::: "memory");

        #pragma unroll
        for (int c = 0; c < 2; ++c) {
            short8 ap = *(const short8*)&Ps[w][l16 * 64 + ((((c << 2) + quad) ^ (l16 & 7)) << 3)];
            #pragma unroll
            for (int dt = 0; dt < 4; ++dt) {
                short8 bv8 = *(const short8*)&Vs[(dt * 16 + l16) * 72 + c * 32 + quad * 8];
                o[dt] = __builtin_amdgcn_mfma_f32_16x16x32_bf16(ap, bv8, o[dt], 0, 0, 0);
            }
        }
    }

    const size_t pbase = ((size_t)(ks * 16 + bh)) * SEQ;
    #pragma unroll
    for (int r = 0; r < 4; ++r) {
        float L = l_acc[r];
        #pragma unroll
        for (int msk = 1; msk < 16; msk <<= 1) L += __shfl_xor(L, msk);
        int qrow = qbase + quad * 4 + r;
        if (l16 == 0) Lpart[pbase + qrow] = L;
        #pragma unroll
        for (int dt = 0; dt < 4; ++dt)
            Opart[(pbase + qrow) * HEAD_DIM + dt * 16 + l16] = o[dt][r];
    }
}

// ---------------------------------------------------------------------------
// Combine 4 split-K attention partials: ctx = sum(O)/sum(l), bf16 [B,S,D].
// ---------------------------------------------------------------------------
__global__ __launch_bounds__(256) void attn_comb_k(
    const float* __restrict__ Op, const float* __restrict__ Lp,
    ushort_t* __restrict__ ctx)
{
    int g = blockIdx.x * 256 + threadIdx.x;      // 0..524287
    int d4 = g & 15;
    int q  = (g >> 4) & 2047;
    int bh = g >> 15;
    float ax = 0.f, ay = 0.f, az = 0.f, aw = 0.f, L = 0.f;
    #pragma unroll
    for (int ks = 0; ks < 4; ++ks) {
        size_t row = ((size_t)(ks * 16 + bh) * SEQ + q) * HEAD_DIM;
        float4 a = ((const float4*)(Op + row))[d4];
        ax += a.x; ay += a.y; az += a.z; aw += a.w;
        L += Lp[ks * 16 * SEQ + bh * SEQ + q];
    }
    float inv = 1.0f / L;
    ushort4 o4;
    o4.x = f2bf(ax * inv);
    o4.y = f2bf(ay * inv);
    o4.z = f2bf(az * inv);
    o4.w = f2bf(aw * inv);
    int bb = bh >> 3, hh = bh & 7;
    *(ushort4*)&ctx[((size_t)(bb * SEQ + q)) * D_MODEL + hh * HEAD_DIM + d4 * 4] = o4;
}

// ---------------------------------------------------------------------------
// Residual + LayerNorm over split-K partials:
// O[row] = LN(X + P0 + P1 + bias) * gamma + beta; optional bf16 copy.
// ---------------------------------------------------------------------------
template <int WRITE_BF>
__global__ __launch_bounds__(256) void add_ln_k(
    const float* __restrict__ X, const float* __restrict__ P0,
    const float* __restrict__ P1, const float* __restrict__ bias,
    const float* __restrict__ gam, const float* __restrict__ bet,
    float* __restrict__ O, ushort_t* __restrict__ Ob)
{
    const int row = blockIdx.x;
    const int t = threadIdx.x;
    const size_t ro = (size_t)row * D_MODEL;

    float v0 = X[ro + t]       + P0[ro + t]       + P1[ro + t]       + bias[t];
    float v1 = X[ro + t + 256] + P0[ro + t + 256] + P1[ro + t + 256] + bias[t + 256];
    float s = v0 + v1;
    float ss = v0 * v0 + v1 * v1;
    #pragma unroll
    for (int off = 32; off > 0; off >>= 1) {
        s  += __shfl_down(s, off);
        ss += __shfl_down(ss, off);
    }
    __shared__ float sb[4], ssb[4];
    if ((t & 63) == 0) { sb[t >> 6] = s; ssb[t >> 6] = ss; }
    __syncthreads();
    float S  = sb[0] + sb[1] + sb[2] + sb[3];
    float SS = ssb[0] + ssb[1] + ssb[2] + ssb[3];
    float mu  = S * (1.0f / D_MODEL);
    float var = SS * (1.0f / D_MODEL) - mu * mu;
    float inv = rsqrtf(var + 1e-5f);
    float o0 = (v0 - mu) * inv * gam[t] + bet[t];
    float o1 = (v1 - mu) * inv * gam[t + 256] + bet[t + 256];
    O[ro + t]       = o0;
    O[ro + t + 256] = o1;
    if (WRITE_BF) {
        Ob[ro + t]       = f2bf(o0);
        Ob[ro + t + 256] = f2bf(o1);
    }
}

// ---------------------------------------------------------------------------
extern "C" void kernel_launch(void* const* d_in, const int* in_sizes, int n_in,
                              void* d_out, int out_size, void* d_ws, size_t ws_size,
                              hipStream_t stream)
{
    const float* x   = (const float*)d_in[0];
    const float* Wq  = (const float*)d_in[1];
    const float* bq  = (const float*)d_in[2];
    const float* Wk  = (const float*)d_in[3];
    const float* bk  = (const float*)d_in[4];
    const float* Wv  = (const float*)d_in[5];
    const float* bv  = (const float*)d_in[6];
    const float* Wo  = (const float*)d_in[7];
    const float* bo  = (const float*)d_in[8];
    const float* W1  = (const float*)d_in[9];
    const float* b1  = (const float*)d_in[10];
    const float* W2  = (const float*)d_in[11];
    const float* b2  = (const float*)d_in[12];
    const float* g1  = (const float*)d_in[13];
    const float* be1 = (const float*)d_in[14];
    const float* g2  = (const float*)d_in[15];
    const float* be2 = (const float*)d_in[16];
    float* out = (float*)d_out;
    float* ws  = (float*)d_ws;

    // float-unit offsets; max end 15,335,424 fl = 61.3 MB (lifetime-overlaid)
    ushort_t* WoT   = (ushort_t*)(ws);               // [512][512] bf16
    ushort_t* W1T   = (ushort_t*)(ws + 131072);      // [2048][512]
    ushort_t* W2T   = (ushort_t*)(ws + 655360);      // [512][2048]
    ushort_t* WqkvT = (ushort_t*)(ws + 1179648);     // [1536][512]
    ushort_t* xb    = (ushort_t*)(ws + 1572864);     // [4096][512] bf16
    ushort_t* Qb    = (ushort_t*)(ws + 2621440);     // [16][2048][64]
    ushort_t* Kb    = (ushort_t*)(ws + 3670016);
    ushort_t* VTb   = (ushort_t*)(ws + 4718592);     // [16][64][2048]
    ushort_t* Ctx   = (ushort_t*)(ws + 5767168);     // [4096][512] bf16
    float*    Lpart = ws + 6815744;                  // [4][16][2048]
    float*    Opart = ws + 6946816;                  // [4][16][2048][64] fp32 (attn->comb)
    float*    Hh    = ws + 6946816;                  // [4096][512] fp32 (ln1->, after comb)
    float*    P0    = ws + 9043968;                  // [4096][512] fp32 partial
    float*    P1    = ws + 11141120;                 // [4096][512] fp32 partial
    ushort_t* FF1   = (ushort_t*)(ws + 1572864);     // [4096][2048] bf16 (xb..VTb, dead by W1)
    ushort_t* Hhb   = (ushort_t*)(ws + 5767168);     // [4096][512] bf16 (Ctx slot, dead after Wo)

    // conversions (fused)
    prep_k<<<5120, 256, 0, stream>>>(x, Wq, Wk, Wv, Wo, W1, W2, xb, WqkvT, WoT, W1T, W2T);

    // QKV projection (direct-load MFMA): 768 blocks, 3072 waves
    gemm_dl_qkv<<<dim3(6, 128), 256, 0, stream>>>(xb, WqkvT, bq, bk, bv, Qb, Kb, VTb);

    // flash attention split-K x4 -> partials -> combine
    attn_mfma_k<<<dim3(16, 32, 4), 256, 0, stream>>>(Qb, Kb, VTb, Opart, Lpart);
    attn_comb_k<<<2048, 256, 0, stream>>>(Opart, Lpart, Ctx);

    // output projection: direct-load, split-K x2, raw partials (bias in LN1)
    gemm_dl_k<2><<<dim3(2, 128, 2), 256, 0, stream>>>(
        Ctx, WoT, nullptr, P0, 512, 512, 256, (size_t)MROWS * D_MODEL);

    // h = LN(x + p0 + p1 + bo)
    add_ln_k<1><<<4096, 256, 0, stream>>>(x, P0, P1, bo, g1, be1, Hh, Hhb);

    // FFN up: direct-load, bf16+bias+ReLU
    gemm_dl_k<1><<<dim3(8, 128), 256, 0, stream>>>(
        Hhb, W1T, b1, FF1, 2048, 512, 512, 0);

    // FFN down: direct-load, split-K x2, raw partials (bias in LN2)
    gemm_dl_k<2><<<dim3(2, 128, 2), 256, 0, stream>>>(
        FF1, W2T, nullptr, P0, 512, 2048, 1024, (size_t)MROWS * D_MODEL);

    // out = LN(h + q0 + q1 + b2)
    add_ln_k<0><<<4096, 256, 0, stream>>>(Hh, P0, P1, b2, g2, be2, out, (ushort_t*)nullptr);
}

// Round 7
// 226.635 us; speedup vs baseline: 1.3831x; 1.3831x over previous
//
#include <hip/hip_runtime.h>
#include <cmath>

#define D_MODEL 512
#define N_HEADS 8
#define HEAD_DIM 64
#define D_FF 2048
#define SEQ 2048
#define BATCH 2
#define MROWS (BATCH * SEQ) /* 4096 */

typedef __attribute__((ext_vector_type(8))) short short8;
typedef __attribute__((ext_vector_type(4))) float float4v;
typedef unsigned short ushort_t;

static __device__ __forceinline__ ushort_t f2bf(float f) {
    union { float f; unsigned u; } v; v.f = f;
    unsigned r = (v.u + 0x7FFFu + ((v.u >> 16) & 1u)) >> 16;
    return (ushort_t)r;
}
static __device__ __forceinline__ ushort_t f2bf_trunc(float f) {
    union { float f; unsigned u; } v; v.f = f;
    return (ushort_t)(v.u >> 16);
}

// async global->LDS, 16B per lane; LDS dest = wave-uniform base + lane*16
static __device__ __forceinline__ void gload16(const void* g, void* l) {
    __builtin_amdgcn_global_load_lds(
        (__attribute__((address_space(1))) void*)(unsigned long long)g,
        (__attribute__((address_space(3))) void*)(unsigned)(unsigned long long)l,
        16, 0, 0);
}

// ---------------------------------------------------------------------------
// prep: weight transpose/convert (tiles 0..3071) + x fp32->bf16 (3072..5119)
// ---------------------------------------------------------------------------
__global__ __launch_bounds__(256) void prep_k(
    const float* __restrict__ x,
    const float* __restrict__ Wq, const float* __restrict__ Wk,
    const float* __restrict__ Wv, const float* __restrict__ Wo,
    const float* __restrict__ W1, const float* __restrict__ W2,
    ushort_t* __restrict__ xb,
    ushort_t* __restrict__ WqkvT, ushort_t* __restrict__ WoT,
    ushort_t* __restrict__ W1T, ushort_t* __restrict__ W2T)
{
    int tile = blockIdx.x;
    if (tile >= 3072) {                    // x -> bf16
        int i = (tile - 3072) * 256 + threadIdx.x;
        float4 f = ((const float4*)x)[i];
        ushort4 o;
        o.x = f2bf(f.x); o.y = f2bf(f.y); o.z = f2bf(f.z); o.w = f2bf(f.w);
        ((ushort4*)xb)[i] = o;
        return;
    }
    const float* src; ushort_t* dst; int Kd, Nd, tloc;
    if (tile < 1024) {
        int wsel = tile >> 8; tloc = tile & 255; Kd = 512; Nd = 512;
        if (wsel == 0)      { src = Wq; dst = WqkvT; }
        else if (wsel == 1) { src = Wk; dst = WqkvT + (size_t)512 * 512; }
        else if (wsel == 2) { src = Wv; dst = WqkvT + (size_t)1024 * 512; }
        else                { src = Wo; dst = WoT; }
    } else if (tile < 2048) { tloc = tile - 1024; Kd = 512;  Nd = 2048; src = W1; dst = W1T; }
    else                    { tloc = tile - 2048; Kd = 2048; Nd = 512;  src = W2; dst = W2T; }
    int tn = Nd >> 5;
    int k0 = (tloc / tn) << 5, n0 = (tloc % tn) << 5;
    __shared__ float tl[32][33];
    int c = threadIdx.x & 31, r = threadIdx.x >> 5;
    #pragma unroll
    for (int i = 0; i < 4; ++i)
        tl[r + i * 8][c] = src[(size_t)(k0 + r + i * 8) * Nd + n0 + c];
    __syncthreads();
    #pragma unroll
    for (int i = 0; i < 4; ++i)
        dst[(size_t)(n0 + r + i * 8) * Kd + k0 + c] = f2bf(tl[c][r + i * 8]);
}

// ---------------------------------------------------------------------------
// MFMA bf16 GEMM core v2: BM=64, BN=128, BK=128, XOR-swizzled LDS.
// LDS layout: row-major, 16B chunks; row r's physical chunk p holds global
// k-chunk p^(r&7). Staged via global_load_lds (per-lane global addr carries
// the swizzle; LDS dest stays linear). Fragment reads hit 2 lanes/bank (free).
// 4 waves in 2x2 grid, wave tile 32x64. One barrier pair per 128 k.
// ---------------------------------------------------------------------------
template <int MODE>  // 0 = fp32+bias; 1 = bf16+bias+ReLU; 2 = fp32 raw split-K partial
__global__ __launch_bounds__(256) void gemm_std_k(
    const ushort_t* __restrict__ A, const ushort_t* __restrict__ BT,
    const float* __restrict__ bias, void* __restrict__ Cv,
    int N, int K, int Klen, size_t zstride)
{
    __shared__ ushort_t As[64 * 128];    // 16 KB
    __shared__ ushort_t Bs[128 * 128];   // 32 KB

    const int t = threadIdx.x;
    const int w = t >> 6, lane = t & 63, l16 = lane & 15, quad = lane >> 4;
    const int m0 = blockIdx.y * 64;
    const int n0 = blockIdx.x * 128;
    const int kbase = blockIdx.z * Klen;
    const int mbase = (w >> 1) * 32;
    const int nbase = (w & 1) * 64;
    const int lrow = lane >> 4;          // 0..3 (row within 4-row staging group)
    const int lchunk = lane & 15;        // 0..15 (16B chunk within 256B row)

    float4v acc[2][4];
    #pragma unroll
    for (int mt = 0; mt < 2; ++mt)
        #pragma unroll
        for (int nt = 0; nt < 4; ++nt)
            acc[mt][nt] = (float4v){0.f, 0.f, 0.f, 0.f};

    for (int ks = kbase; ks < kbase + Klen; ks += 128) {
        __syncthreads();
        for (int c = w; c < 16; c += 4) {      // A: 64 rows in 16 groups of 4
            int rl = c * 4 + lrow;
            gload16(A + (size_t)(m0 + rl) * K + ks + ((lchunk ^ (rl & 7)) << 3),
                    &As[c * 512]);
        }
        for (int c = w; c < 32; c += 4) {      // B: 128 rows in 32 groups of 4
            int rl = c * 4 + lrow;
            gload16(BT + (size_t)(n0 + rl) * K + ks + ((lchunk ^ (rl & 7)) << 3),
                    &Bs[c * 512]);
        }
        __syncthreads();

        #pragma unroll
        for (int co = 0; co < 4; ++co) {
            const int poff = (((co * 4 + quad) ^ (l16 & 7)) << 3);
            short8 af[2], bf8[4];
            #pragma unroll
            for (int mt = 0; mt < 2; ++mt)
                af[mt] = *(const short8*)&As[(mbase + mt * 16 + l16) * 128 + poff];
            #pragma unroll
            for (int nt = 0; nt < 4; ++nt)
                bf8[nt] = *(const short8*)&Bs[(nbase + nt * 16 + l16) * 128 + poff];
            #pragma unroll
            for (int mt = 0; mt < 2; ++mt)
                #pragma unroll
                for (int nt = 0; nt < 4; ++nt)
                    acc[mt][nt] = __builtin_amdgcn_mfma_f32_16x16x32_bf16(
                        af[mt], bf8[nt], acc[mt][nt], 0, 0, 0);
        }
    }

    float* Cf = (float*)Cv + blockIdx.z * zstride;
    #pragma unroll
    for (int mt = 0; mt < 2; ++mt) {
        #pragma unroll
        for (int nt = 0; nt < 4; ++nt) {
            int gcol = n0 + nbase + nt * 16 + l16;
            float b = (MODE == 2) ? 0.f : bias[gcol];
            #pragma unroll
            for (int r = 0; r < 4; ++r) {
                int grow = m0 + mbase + mt * 16 + quad * 4 + r;
                float v = acc[mt][nt][r] + b;
                if (MODE == 1) v = fmaxf(v, 0.f);
                if (MODE == 1) ((ushort_t*)Cv)[(size_t)grow * N + gcol] = f2bf(v);
                else           Cf[(size_t)grow * N + gcol] = v;
            }
        }
    }
}

// ---------------------------------------------------------------------------
// Fused QKV GEMM on the v2 core. Block-uniform epilogue select (128 | 512).
// Q scale folds 1/sqrt(64) and log2(e).
// ---------------------------------------------------------------------------
__global__ __launch_bounds__(256) void gemm_qkv_k(
    const ushort_t* __restrict__ A, const ushort_t* __restrict__ BT,
    const float* __restrict__ bq, const float* __restrict__ bk,
    const float* __restrict__ bv,
    ushort_t* __restrict__ Qb, ushort_t* __restrict__ Kb,
    ushort_t* __restrict__ VTb)
{
    __shared__ ushort_t As[64 * 128];
    __shared__ ushort_t Bs[128 * 128];

    const int t = threadIdx.x;
    const int w = t >> 6, lane = t & 63, l16 = lane & 15, quad = lane >> 4;
    const int m0 = blockIdx.y * 64;
    const int n0 = blockIdx.x * 128;
    const int mbase = (w >> 1) * 32;
    const int nbase = (w & 1) * 64;
    const int lrow = lane >> 4;
    const int lchunk = lane & 15;
    const int K = 512;

    float4v acc[2][4];
    #pragma unroll
    for (int mt = 0; mt < 2; ++mt)
        #pragma unroll
        for (int nt = 0; nt < 4; ++nt)
            acc[mt][nt] = (float4v){0.f, 0.f, 0.f, 0.f};

    for (int ks = 0; ks < 512; ks += 128) {
        __syncthreads();
        for (int c = w; c < 16; c += 4) {
            int rl = c * 4 + lrow;
            gload16(A + (size_t)(m0 + rl) * K + ks + ((lchunk ^ (rl & 7)) << 3),
                    &As[c * 512]);
        }
        for (int c = w; c < 32; c += 4) {
            int rl = c * 4 + lrow;
            gload16(BT + (size_t)(n0 + rl) * K + ks + ((lchunk ^ (rl & 7)) << 3),
                    &Bs[c * 512]);
        }
        __syncthreads();

        #pragma unroll
        for (int co = 0; co < 4; ++co) {
            const int poff = (((co * 4 + quad) ^ (l16 & 7)) << 3);
            short8 af[2], bf8[4];
            #pragma unroll
            for (int mt = 0; mt < 2; ++mt)
                af[mt] = *(const short8*)&As[(mbase + mt * 16 + l16) * 128 + poff];
            #pragma unroll
            for (int nt = 0; nt < 4; ++nt)
                bf8[nt] = *(const short8*)&Bs[(nbase + nt * 16 + l16) * 128 + poff];
            #pragma unroll
            for (int mt = 0; mt < 2; ++mt)
                #pragma unroll
                for (int nt = 0; nt < 4; ++nt)
                    acc[mt][nt] = __builtin_amdgcn_mfma_f32_16x16x32_bf16(
                        af[mt], bf8[nt], acc[mt][nt], 0, 0, 0);
        }
    }

    const int tsel = n0 >> 9;                       // 0=Q 1=K 2=V (block-uniform)
    const float* bias = (tsel == 0) ? bq : (tsel == 1) ? bk : bv;
    const float scl = (tsel == 0) ? 0.18033688f : 1.0f;  // 0.125 * log2(e)
    ushort_t* dst = (tsel == 0) ? Qb : Kb;

    #pragma unroll
    for (int mt = 0; mt < 2; ++mt) {
        #pragma unroll
        for (int nt = 0; nt < 4; ++nt) {
            int gcol = n0 + nbase + nt * 16 + l16;
            int lcol = gcol - (tsel << 9);
            int h = lcol >> 6, dh = lcol & 63;
            float b = bias[lcol];
            #pragma unroll
            for (int r = 0; r < 4; ++r) {
                int grow = m0 + mbase + mt * 16 + quad * 4 + r;
                int bb = grow >> 11, s = grow & 2047;
                float v = (acc[mt][nt][r] + b) * scl;
                if (tsel < 2)
                    dst[(((size_t)(bb * N_HEADS + h)) * SEQ + s) * HEAD_DIM + dh] = f2bf(v);
                else
                    VTb[(((size_t)(bb * N_HEADS + h)) * HEAD_DIM + dh) * SEQ + s] = f2bf(v);
            }
        }
    }
}

// ---------------------------------------------------------------------------
// bf16 MFMA flash attention: fixed-max exp2 softmax, split-K x2.
// Grid (16 bh, 32 qt, 2 ks). Ps XOR-swizzled (conflict-free).
// ---------------------------------------------------------------------------
__global__ __launch_bounds__(256) void attn_mfma_k(
    const ushort_t* __restrict__ Qg, const ushort_t* __restrict__ Kg,
    const ushort_t* __restrict__ VTg,
    float* __restrict__ Opart, float* __restrict__ Lpart)
{
    __shared__ __align__(16) ushort_t Ks[64 * 72];
    __shared__ __align__(16) ushort_t Vs[64 * 72];
    __shared__ __align__(16) ushort_t Ps[4][16 * 64];   // swizzled

    const int bh = blockIdx.x;
    const int q0 = blockIdx.y * 64;
    const int ks = blockIdx.z;
    const int t = threadIdx.x;
    const int w = t >> 6;
    const int lane = t & 63;
    const int l16 = lane & 15;
    const int quad = lane >> 4;
    const int qbase = q0 + w * 16;
    const float M2 = 14.4269504f;   // 10*log2(e); scores pre-scaled by log2(e)/8

    short8 aq[2];
    {
        const ushort_t* qp = Qg + ((size_t)bh * SEQ + qbase + l16) * HEAD_DIM + quad * 8;
        aq[0] = *(const short8*)(qp);
        aq[1] = *(const short8*)(qp + 32);
    }

    float4v o[4] = {};
    float l_acc[4] = {0.f, 0.f, 0.f, 0.f};

    for (int kt = 0; kt < 16; ++kt) {
        const int kbase = ks * 1024 + kt * 64;
        __syncthreads();
        #pragma unroll
        for (int lit = 0; lit < 2; ++lit) {
            int flat = lit * 256 + t;
            int row = flat >> 3;
            int c0 = (flat & 7) * 8;
            *(short8*)&Ks[row * 72 + c0] =
                *(const short8*)(Kg + ((size_t)bh * SEQ + kbase + row) * HEAD_DIM + c0);
            *(short8*)&Vs[row * 72 + c0] =
                *(const short8*)(VTg + ((size_t)bh * HEAD_DIM + row) * SEQ + kbase + c0);
        }
        __syncthreads();

        float4v s[4];
        #pragma unroll
        for (int nt = 0; nt < 4; ++nt) s[nt] = (float4v){0.f, 0.f, 0.f, 0.f};
        #pragma unroll
        for (int c = 0; c < 2; ++c) {
            #pragma unroll
            for (int nt = 0; nt < 4; ++nt) {
                short8 bk8 = *(const short8*)&Ks[(nt * 16 + l16) * 72 + c * 32 + quad * 8];
                s[nt] = __builtin_amdgcn_mfma_f32_16x16x32_bf16(aq[c], bk8, s[nt], 0, 0, 0);
            }
        }

        #pragma unroll
        for (int nt = 0; nt < 4; ++nt) {
            #pragma unroll
            for (int r = 0; r < 4; ++r) {
                float p = exp2f(s[nt][r] - M2);
                s[nt][r] = p;
                l_acc[r] += p;
            }
        }

        // P -> per-wave LDS, swizzled: (row,key) at row*64 + ((key>>3)^(row&7))*8 + (key&7)
        #pragma unroll
        for (int nt = 0; nt < 4; ++nt)
            #pragma unroll
            for (int r = 0; r < 4; ++r) {
                int row = quad * 4 + r;
                int key = nt * 16 + l16;
                Ps[w][row * 64 + (((key >> 3) ^ (row & 7)) << 3) + (key & 7)] =
                    f2bf_trunc(s[nt][r]);
            }
        asm volatile("s_waitcnt lgkmcnt(0)" ::: "memory");

        #pragma unroll
        for (int c = 0; c < 2; ++c) {
            short8 ap = *(const short8*)&Ps[w][l16 * 64 + ((((c << 2) + quad) ^ (l16 & 7)) << 3)];
            #pragma unroll
            for (int dt = 0; dt < 4; ++dt) {
                short8 bv8 = *(const short8*)&Vs[(dt * 16 + l16) * 72 + c * 32 + quad * 8];
                o[dt] = __builtin_amdgcn_mfma_f32_16x16x32_bf16(ap, bv8, o[dt], 0, 0, 0);
            }
        }
    }

    const size_t pbase = ((size_t)(ks * 16 + bh)) * SEQ;
    #pragma unroll
    for (int r = 0; r < 4; ++r) {
        float L = l_acc[r];
        #pragma unroll
        for (int msk = 1; msk < 16; msk <<= 1) L += __shfl_xor(L, msk);
        int qrow = qbase + quad * 4 + r;
        if (l16 == 0) Lpart[pbase + qrow] = L;
        #pragma unroll
        for (int dt = 0; dt < 4; ++dt)
            Opart[(pbase + qrow) * HEAD_DIM + dt * 16 + l16] = o[dt][r];
    }
}

// ---------------------------------------------------------------------------
// Combine 2 split-K attention partials: ctx = sum(O)/sum(l), bf16 [B,S,D].
// ---------------------------------------------------------------------------
__global__ __launch_bounds__(256) void attn_comb_k(
    const float* __restrict__ Op, const float* __restrict__ Lp,
    ushort_t* __restrict__ ctx)
{
    int g = blockIdx.x * 256 + threadIdx.x;      // 0..524287
    int d4 = g & 15;
    int q  = (g >> 4) & 2047;
    int bh = g >> 15;
    float ax = 0.f, ay = 0.f, az = 0.f, aw = 0.f, L = 0.f;
    #pragma unroll
    for (int ks = 0; ks < 2; ++ks) {
        size_t row = ((size_t)(ks * 16 + bh) * SEQ + q) * HEAD_DIM;
        float4 a = ((const float4*)(Op + row))[d4];
        ax += a.x; ay += a.y; az += a.z; aw += a.w;
        L += Lp[ks * 16 * SEQ + bh * SEQ + q];
    }
    float inv = 1.0f / L;
    ushort4 o4;
    o4.x = f2bf(ax * inv);
    o4.y = f2bf(ay * inv);
    o4.z = f2bf(az * inv);
    o4.w = f2bf(aw * inv);
    int bb = bh >> 3, hh = bh & 7;
    *(ushort4*)&ctx[((size_t)(bb * SEQ + q)) * D_MODEL + hh * HEAD_DIM + d4 * 4] = o4;
}

// ---------------------------------------------------------------------------
// Residual + LayerNorm over split-K partials:
// O[row] = LN(X + P0 + P1 + bias) * gamma + beta; optional bf16 copy.
// ---------------------------------------------------------------------------
template <int WRITE_BF>
__global__ __launch_bounds__(256) void add_ln_k(
    const float* __restrict__ X, const float* __restrict__ P0,
    const float* __restrict__ P1, const float* __restrict__ bias,
    const float* __restrict__ gam, const float* __restrict__ bet,
    float* __restrict__ O, ushort_t* __restrict__ Ob)
{
    const int row = blockIdx.x;
    const int t = threadIdx.x;
    const size_t ro = (size_t)row * D_MODEL;

    float v0 = X[ro + t]       + P0[ro + t]       + P1[ro + t]       + bias[t];
    float v1 = X[ro + t + 256] + P0[ro + t + 256] + P1[ro + t + 256] + bias[t + 256];
    float s = v0 + v1;
    float ss = v0 * v0 + v1 * v1;
    #pragma unroll
    for (int off = 32; off > 0; off >>= 1) {
        s  += __shfl_down(s, off);
        ss += __shfl_down(ss, off);
    }
    __shared__ float sb[4], ssb[4];
    if ((t & 63) == 0) { sb[t >> 6] = s; ssb[t >> 6] = ss; }
    __syncthreads();
    float S  = sb[0] + sb[1] + sb[2] + sb[3];
    float SS = ssb[0] + ssb[1] + ssb[2] + ssb[3];
    float mu  = S * (1.0f / D_MODEL);
    float var = SS * (1.0f / D_MODEL) - mu * mu;
    float inv = rsqrtf(var + 1e-5f);
    float o0 = (v0 - mu) * inv * gam[t] + bet[t];
    float o1 = (v1 - mu) * inv * gam[t + 256] + bet[t + 256];
    O[ro + t]       = o0;
    O[ro + t + 256] = o1;
    if (WRITE_BF) {
        Ob[ro + t]       = f2bf(o0);
        Ob[ro + t + 256] = f2bf(o1);
    }
}

// ---------------------------------------------------------------------------
extern "C" void kernel_launch(void* const* d_in, const int* in_sizes, int n_in,
                              void* d_out, int out_size, void* d_ws, size_t ws_size,
                              hipStream_t stream)
{
    const float* x   = (const float*)d_in[0];
    const float* Wq  = (const float*)d_in[1];
    const float* bq  = (const float*)d_in[2];
    const float* Wk  = (const float*)d_in[3];
    const float* bk  = (const float*)d_in[4];
    const float* Wv  = (const float*)d_in[5];
    const float* bv  = (const float*)d_in[6];
    const float* Wo  = (const float*)d_in[7];
    const float* bo  = (const float*)d_in[8];
    const float* W1  = (const float*)d_in[9];
    const float* b1  = (const float*)d_in[10];
    const float* W2  = (const float*)d_in[11];
    const float* b2  = (const float*)d_in[12];
    const float* g1  = (const float*)d_in[13];
    const float* be1 = (const float*)d_in[14];
    const float* g2  = (const float*)d_in[15];
    const float* be2 = (const float*)d_in[16];
    float* out = (float*)d_out;
    float* ws  = (float*)d_ws;

    // float-unit offsets; max end 13,172,736 fl = 52.7 MB (lifetime-overlaid)
    ushort_t* WoT   = (ushort_t*)(ws);               // [512][512] bf16
    ushort_t* W1T   = (ushort_t*)(ws + 131072);      // [2048][512]
    ushort_t* W2T   = (ushort_t*)(ws + 655360);      // [512][2048]
    ushort_t* WqkvT = (ushort_t*)(ws + 1179648);     // [1536][512]
    ushort_t* xb    = (ushort_t*)(ws + 1572864);     // [4096][512] bf16
    ushort_t* Qb    = (ushort_t*)(ws + 2621440);     // [16][2048][64]
    ushort_t* Kb    = (ushort_t*)(ws + 3670016);
    ushort_t* VTb   = (ushort_t*)(ws + 4718592);     // [16][64][2048]
    ushort_t* Ctx   = (ushort_t*)(ws + 5767168);     // [4096][512] bf16
    float*    Lpart = ws + 6815744;                  // [2][16][2048]
    float*    Hh    = ws + 6881280;                  // [4096][512] fp32
    float*    P0    = ws + 8978432;                  // [4096][512] fp32 partial
    float*    P1    = ws + 11075584;                 // [4096][512] fp32 partial
    float*    Opart = ws + 8978432;                  // [2][16][2048][64] (P0+P1 slot, dead before Wo)
    ushort_t* FF1   = (ushort_t*)(ws + 1572864);     // [4096][2048] bf16 (xb/Qb slot, dead by W1)
    ushort_t* Hhb   = (ushort_t*)(ws + 5767168);     // [4096][512] bf16 (Ctx slot, dead after Wo)

    // conversions (fused)
    prep_k<<<5120, 256, 0, stream>>>(x, Wq, Wk, Wv, Wo, W1, W2, xb, WqkvT, WoT, W1T, W2T);

    // QKV projection: BM=64, BK=128 swizzled core; 768 blocks
    gemm_qkv_k<<<dim3(12, 64), 256, 0, stream>>>(xb, WqkvT, bq, bk, bv, Qb, Kb, VTb);

    // flash attention split-K x2 -> partials -> combine
    attn_mfma_k<<<dim3(16, 32, 2), 256, 0, stream>>>(Qb, Kb, VTb, Opart, Lpart);
    attn_comb_k<<<2048, 256, 0, stream>>>(Opart, Lpart, Ctx);

    // output projection: split-K x2, raw fp32 partials (bias folded into LN1); 512 blocks
    gemm_std_k<2><<<dim3(4, 64, 2), 256, 0, stream>>>(
        Ctx, WoT, nullptr, P0, 512, 512, 256, (size_t)MROWS * D_MODEL);

    // h = LN(x + p0 + p1 + bo)
    add_ln_k<1><<<4096, 256, 0, stream>>>(x, P0, P1, bo, g1, be1, Hh, Hhb);

    // FFN up: bf16 + bias + ReLU; 1024 blocks
    gemm_std_k<1><<<dim3(16, 64), 256, 0, stream>>>(
        Hhb, W1T, b1, FF1, 2048, 512, 512, 0);

    // FFN down: split-K x2, raw fp32 partials (bias folded into LN2); 512 blocks
    gemm_std_k<2><<<dim3(4, 64, 2), 256, 0, stream>>>(
        FF1, W2T, nullptr, P0, 512, 2048, 1024, (size_t)MROWS * D_MODEL);

    // out = LN(h + q0 + q1 + b2)
    add_ln_k<0><<<4096, 256, 0, stream>>>(Hh, P0, P1, b2, g2, be2, out, (ushort_t*)nullptr);
}

// Round 8
// 221.079 us; speedup vs baseline: 1.4179x; 1.0251x over previous
//
#include <hip/hip_runtime.h>
#include <cmath>

#define D_MODEL 512
#define N_HEADS 8
#define HEAD_DIM 64
#define D_FF 2048
#define SEQ 2048
#define BATCH 2
#define MROWS (BATCH * SEQ) /* 4096 */

typedef __attribute__((ext_vector_type(8))) short short8;
typedef __attribute__((ext_vector_type(4))) float float4v;
typedef unsigned short ushort_t;

static __device__ __forceinline__ ushort_t f2bf(float f) {
    union { float f; unsigned u; } v; v.f = f;
    unsigned r = (v.u + 0x7FFFu + ((v.u >> 16) & 1u)) >> 16;
    return (ushort_t)r;
}
static __device__ __forceinline__ ushort_t f2bf_trunc(float f) {
    union { float f; unsigned u; } v; v.f = f;
    return (ushort_t)(v.u >> 16);
}

// async global->LDS, 16B per lane; LDS dest = wave-uniform base + lane*16
static __device__ __forceinline__ void gload16(const void* g, void* l) {
    __builtin_amdgcn_global_load_lds(
        (__attribute__((address_space(1))) void*)(unsigned long long)g,
        (__attribute__((address_space(3))) void*)(unsigned)(unsigned long long)l,
        16, 0, 0);
}

// ---------------------------------------------------------------------------
// prep: weight transpose/convert (tiles 0..3071) + x fp32->bf16 (3072..5119)
// ---------------------------------------------------------------------------
__global__ __launch_bounds__(256) void prep_k(
    const float* __restrict__ x,
    const float* __restrict__ Wq, const float* __restrict__ Wk,
    const float* __restrict__ Wv, const float* __restrict__ Wo,
    const float* __restrict__ W1, const float* __restrict__ W2,
    ushort_t* __restrict__ xb,
    ushort_t* __restrict__ WqkvT, ushort_t* __restrict__ WoT,
    ushort_t* __restrict__ W1T, ushort_t* __restrict__ W2T)
{
    int tile = blockIdx.x;
    if (tile >= 3072) {                    // x -> bf16
        int i = (tile - 3072) * 256 + threadIdx.x;
        float4 f = ((const float4*)x)[i];
        ushort4 o;
        o.x = f2bf(f.x); o.y = f2bf(f.y); o.z = f2bf(f.z); o.w = f2bf(f.w);
        ((ushort4*)xb)[i] = o;
        return;
    }
    const float* src; ushort_t* dst; int Kd, Nd, tloc;
    if (tile < 1024) {
        int wsel = tile >> 8; tloc = tile & 255; Kd = 512; Nd = 512;
        if (wsel == 0)      { src = Wq; dst = WqkvT; }
        else if (wsel == 1) { src = Wk; dst = WqkvT + (size_t)512 * 512; }
        else if (wsel == 2) { src = Wv; dst = WqkvT + (size_t)1024 * 512; }
        else                { src = Wo; dst = WoT; }
    } else if (tile < 2048) { tloc = tile - 1024; Kd = 512;  Nd = 2048; src = W1; dst = W1T; }
    else                    { tloc = tile - 2048; Kd = 2048; Nd = 512;  src = W2; dst = W2T; }
    int tn = Nd >> 5;
    int k0 = (tloc / tn) << 5, n0 = (tloc % tn) << 5;
    __shared__ float tl[32][33];
    int c = threadIdx.x & 31, r = threadIdx.x >> 5;
    #pragma unroll
    for (int i = 0; i < 4; ++i)
        tl[r + i * 8][c] = src[(size_t)(k0 + r + i * 8) * Nd + n0 + c];
    __syncthreads();
    #pragma unroll
    for (int i = 0; i < 4; ++i)
        dst[(size_t)(n0 + r + i * 8) * Kd + k0 + c] = f2bf(tl[c][r + i * 8]);
}

// ---------------------------------------------------------------------------
// MFMA bf16 GEMM core v2 (round-7): BM=64, BN=128, BK=128, XOR-swizzled LDS.
// ---------------------------------------------------------------------------
template <int MODE>  // 0 = fp32+bias; 1 = bf16+bias+ReLU; 2 = fp32 raw split-K partial
__global__ __launch_bounds__(256) void gemm_std_k(
    const ushort_t* __restrict__ A, const ushort_t* __restrict__ BT,
    const float* __restrict__ bias, void* __restrict__ Cv,
    int N, int K, int Klen, size_t zstride)
{
    __shared__ ushort_t As[64 * 128];    // 16 KB
    __shared__ ushort_t Bs[128 * 128];   // 32 KB

    const int t = threadIdx.x;
    const int w = t >> 6, lane = t & 63, l16 = lane & 15, quad = lane >> 4;
    const int m0 = blockIdx.y * 64;
    const int n0 = blockIdx.x * 128;
    const int kbase = blockIdx.z * Klen;
    const int mbase = (w >> 1) * 32;
    const int nbase = (w & 1) * 64;
    const int lrow = lane >> 4;
    const int lchunk = lane & 15;

    float4v acc[2][4];
    #pragma unroll
    for (int mt = 0; mt < 2; ++mt)
        #pragma unroll
        for (int nt = 0; nt < 4; ++nt)
            acc[mt][nt] = (float4v){0.f, 0.f, 0.f, 0.f};

    for (int ks = kbase; ks < kbase + Klen; ks += 128) {
        __syncthreads();
        for (int c = w; c < 16; c += 4) {
            int rl = c * 4 + lrow;
            gload16(A + (size_t)(m0 + rl) * K + ks + ((lchunk ^ (rl & 7)) << 3),
                    &As[c * 512]);
        }
        for (int c = w; c < 32; c += 4) {
            int rl = c * 4 + lrow;
            gload16(BT + (size_t)(n0 + rl) * K + ks + ((lchunk ^ (rl & 7)) << 3),
                    &Bs[c * 512]);
        }
        __syncthreads();

        #pragma unroll
        for (int co = 0; co < 4; ++co) {
            const int poff = (((co * 4 + quad) ^ (l16 & 7)) << 3);
            short8 af[2], bf8[4];
            #pragma unroll
            for (int mt = 0; mt < 2; ++mt)
                af[mt] = *(const short8*)&As[(mbase + mt * 16 + l16) * 128 + poff];
            #pragma unroll
            for (int nt = 0; nt < 4; ++nt)
                bf8[nt] = *(const short8*)&Bs[(nbase + nt * 16 + l16) * 128 + poff];
            #pragma unroll
            for (int mt = 0; mt < 2; ++mt)
                #pragma unroll
                for (int nt = 0; nt < 4; ++nt)
                    acc[mt][nt] = __builtin_amdgcn_mfma_f32_16x16x32_bf16(
                        af[mt], bf8[nt], acc[mt][nt], 0, 0, 0);
        }
    }

    float* Cf = (float*)Cv + blockIdx.z * zstride;
    #pragma unroll
    for (int mt = 0; mt < 2; ++mt) {
        #pragma unroll
        for (int nt = 0; nt < 4; ++nt) {
            int gcol = n0 + nbase + nt * 16 + l16;
            float b = (MODE == 2) ? 0.f : bias[gcol];
            #pragma unroll
            for (int r = 0; r < 4; ++r) {
                int grow = m0 + mbase + mt * 16 + quad * 4 + r;
                float v = acc[mt][nt][r] + b;
                if (MODE == 1) v = fmaxf(v, 0.f);
                if (MODE == 1) ((ushort_t*)Cv)[(size_t)grow * N + gcol] = f2bf(v);
                else           Cf[(size_t)grow * N + gcol] = v;
            }
        }
    }
}

// ---------------------------------------------------------------------------
// Fused QKV GEMM on the v2 core. Q scale folds 1/sqrt(64) and log2(e).
// ---------------------------------------------------------------------------
__global__ __launch_bounds__(256) void gemm_qkv_k(
    const ushort_t* __restrict__ A, const ushort_t* __restrict__ BT,
    const float* __restrict__ bq, const float* __restrict__ bk,
    const float* __restrict__ bv,
    ushort_t* __restrict__ Qb, ushort_t* __restrict__ Kb,
    ushort_t* __restrict__ VTb)
{
    __shared__ ushort_t As[64 * 128];
    __shared__ ushort_t Bs[128 * 128];

    const int t = threadIdx.x;
    const int w = t >> 6, lane = t & 63, l16 = lane & 15, quad = lane >> 4;
    const int m0 = blockIdx.y * 64;
    const int n0 = blockIdx.x * 128;
    const int mbase = (w >> 1) * 32;
    const int nbase = (w & 1) * 64;
    const int lrow = lane >> 4;
    const int lchunk = lane & 15;
    const int K = 512;

    float4v acc[2][4];
    #pragma unroll
    for (int mt = 0; mt < 2; ++mt)
        #pragma unroll
        for (int nt = 0; nt < 4; ++nt)
            acc[mt][nt] = (float4v){0.f, 0.f, 0.f, 0.f};

    for (int ks = 0; ks < 512; ks += 128) {
        __syncthreads();
        for (int c = w; c < 16; c += 4) {
            int rl = c * 4 + lrow;
            gload16(A + (size_t)(m0 + rl) * K + ks + ((lchunk ^ (rl & 7)) << 3),
                    &As[c * 512]);
        }
        for (int c = w; c < 32; c += 4) {
            int rl = c * 4 + lrow;
            gload16(BT + (size_t)(n0 + rl) * K + ks + ((lchunk ^ (rl & 7)) << 3),
                    &Bs[c * 512]);
        }
        __syncthreads();

        #pragma unroll
        for (int co = 0; co < 4; ++co) {
            const int poff = (((co * 4 + quad) ^ (l16 & 7)) << 3);
            short8 af[2], bf8[4];
            #pragma unroll
            for (int mt = 0; mt < 2; ++mt)
                af[mt] = *(const short8*)&As[(mbase + mt * 16 + l16) * 128 + poff];
            #pragma unroll
            for (int nt = 0; nt < 4; ++nt)
                bf8[nt] = *(const short8*)&Bs[(nbase + nt * 16 + l16) * 128 + poff];
            #pragma unroll
            for (int mt = 0; mt < 2; ++mt)
                #pragma unroll
                for (int nt = 0; nt < 4; ++nt)
                    acc[mt][nt] = __builtin_amdgcn_mfma_f32_16x16x32_bf16(
                        af[mt], bf8[nt], acc[mt][nt], 0, 0, 0);
        }
    }

    const int tsel = n0 >> 9;                       // 0=Q 1=K 2=V (block-uniform)
    const float* bias = (tsel == 0) ? bq : (tsel == 1) ? bk : bv;
    const float scl = (tsel == 0) ? 0.18033688f : 1.0f;  // 0.125 * log2(e)
    ushort_t* dst = (tsel == 0) ? Qb : Kb;

    #pragma unroll
    for (int mt = 0; mt < 2; ++mt) {
        #pragma unroll
        for (int nt = 0; nt < 4; ++nt) {
            int gcol = n0 + nbase + nt * 16 + l16;
            int lcol = gcol - (tsel << 9);
            int h = lcol >> 6, dh = lcol & 63;
            float b = bias[lcol];
            #pragma unroll
            for (int r = 0; r < 4; ++r) {
                int grow = m0 + mbase + mt * 16 + quad * 4 + r;
                int bb = grow >> 11, s = grow & 2047;
                float v = (acc[mt][nt][r] + b) * scl;
                if (tsel < 2)
                    dst[(((size_t)(bb * N_HEADS + h)) * SEQ + s) * HEAD_DIM + dh] = f2bf(v);
                else
                    VTb[(((size_t)(bb * N_HEADS + h)) * HEAD_DIM + dh) * SEQ + s] = f2bf(v);
            }
        }
    }
}

// ---------------------------------------------------------------------------
// bf16 MFMA flash attention v4: async double-buffered K/V staging via
// global_load_lds (XOR-swizzled, unpadded), raw s_barrier (no vmcnt(0) drain),
// explicit vmcnt(4): tile kt+1's DMA in flight during tile kt's compute.
// Fixed-max exp2 softmax, split-K x2. Grid (16 bh, 32 qt, 2 ks).
// LDS 40 KB -> 4 blocks/CU (grid-exact).
// Swizzle: row r's physical 16B chunk p holds global chunk p^(r&7).
// ---------------------------------------------------------------------------
__global__ __launch_bounds__(256) void attn_mfma_k(
    const ushort_t* __restrict__ Qg, const ushort_t* __restrict__ Kg,
    const ushort_t* __restrict__ VTg,
    float* __restrict__ Opart, float* __restrict__ Lpart)
{
    __shared__ __align__(16) ushort_t Kbuf[2][64 * 64];   // 8 KB each
    __shared__ __align__(16) ushort_t Vbuf[2][64 * 64];
    __shared__ __align__(16) ushort_t Ps[4][16 * 64];     // swizzled, per-wave

    const int bh = blockIdx.x;
    const int q0 = blockIdx.y * 64;
    const int ks = blockIdx.z;
    const int t = threadIdx.x;
    const int w = t >> 6;
    const int lane = t & 63;
    const int l16 = lane & 15;
    const int quad = lane >> 4;
    const int qbase = q0 + w * 16;
    const float M2 = 14.4269504f;   // 10*log2(e); scores pre-scaled by log2(e)/8

    // staging geometry: chunk id = batch*256 + t; row = id>>3, phys = id&7,
    // global chunk g = phys ^ (row&7). LDS dest wave-uniform base + lane*16.
    const int r0 = t >> 3;                 // rows 0..31  (batch 0)
    const int r1 = r0 + 32;                // rows 32..63 (batch 1)
    const int g0 = (t & 7) ^ (r0 & 7);
    const int g1 = (t & 7) ^ (r1 & 7);
    const size_t kgrow = (size_t)bh * SEQ;         // + key
    const size_t vgrow = (size_t)bh * HEAD_DIM;    // + d

#define ATTN_STAGE(b, kb)                                                       \
    {                                                                           \
        gload16(Kg + (kgrow + (kb) + r0) * HEAD_DIM + g0 * 8, &Kbuf[b][w * 512]);          \
        gload16(Kg + (kgrow + (kb) + r1) * HEAD_DIM + g1 * 8, &Kbuf[b][2048 + w * 512]);   \
        gload16(VTg + (vgrow + r0) * SEQ + (kb) + g0 * 8, &Vbuf[b][w * 512]);              \
        gload16(VTg + (vgrow + r1) * SEQ + (kb) + g1 * 8, &Vbuf[b][2048 + w * 512]);       \
    }

    short8 aq[2];
    {
        const ushort_t* qp = Qg + ((size_t)bh * SEQ + qbase + l16) * HEAD_DIM + quad * 8;
        aq[0] = *(const short8*)(qp);
        aq[1] = *(const short8*)(qp + 32);
    }

    float4v o[4] = {};
    float l_acc[4] = {0.f, 0.f, 0.f, 0.f};

    ATTN_STAGE(0, ks * 1024)

    for (int kt = 0; kt < 16; ++kt) {
        const int cur = kt & 1;
        if (kt < 15) {
            ATTN_STAGE(cur ^ 1, ks * 1024 + (kt + 1) * 64)
            asm volatile("s_waitcnt vmcnt(4)" ::: "memory");  // tile kt landed (mine)
        } else {
            asm volatile("s_waitcnt vmcnt(0)" ::: "memory");
        }
        asm volatile("s_barrier" ::: "memory");               // tile kt landed (all)

        const ushort_t* Kc = Kbuf[cur];
        const ushort_t* Vc = Vbuf[cur];

        float4v s[4];
        #pragma unroll
        for (int nt = 0; nt < 4; ++nt) s[nt] = (float4v){0.f, 0.f, 0.f, 0.f};
        #pragma unroll
        for (int c = 0; c < 2; ++c) {
            const int poff = (((c * 4 + quad) ^ (l16 & 7)) << 3);
            #pragma unroll
            for (int nt = 0; nt < 4; ++nt) {
                short8 bk8 = *(const short8*)&Kc[(nt * 16 + l16) * 64 + poff];
                s[nt] = __builtin_amdgcn_mfma_f32_16x16x32_bf16(aq[c], bk8, s[nt], 0, 0, 0);
            }
        }

        #pragma unroll
        for (int nt = 0; nt < 4; ++nt) {
            #pragma unroll
            for (int r = 0; r < 4; ++r) {
                float p = exp2f(s[nt][r] - M2);
                s[nt][r] = p;
                l_acc[r] += p;
            }
        }

        // P -> per-wave LDS, swizzled: (row,key) at row*64 + ((key>>3)^(row&7))*8 + (key&7)
        #pragma unroll
        for (int nt = 0; nt < 4; ++nt)
            #pragma unroll
            for (int r = 0; r < 4; ++r) {
                int row = quad * 4 + r;
                int key = nt * 16 + l16;
                Ps[w][row * 64 + (((key >> 3) ^ (row & 7)) << 3) + (key & 7)] =
                    f2bf_trunc(s[nt][r]);
            }
        asm volatile("s_waitcnt lgkmcnt(0)" ::: "memory");    // wave-private Ps visible

        #pragma unroll
        for (int c = 0; c < 2; ++c) {
            short8 ap = *(const short8*)&Ps[w][l16 * 64 + ((((c << 2) + quad) ^ (l16 & 7)) << 3)];
            const int poff = (((c * 4 + quad) ^ (l16 & 7)) << 3);
            #pragma unroll
            for (int dt = 0; dt < 4; ++dt) {
                short8 bv8 = *(const short8*)&Vc[(dt * 16 + l16) * 64 + poff];
                o[dt] = __builtin_amdgcn_mfma_f32_16x16x32_bf16(ap, bv8, o[dt], 0, 0, 0);
            }
        }

        asm volatile("s_barrier" ::: "memory");   // all waves done reading buf[cur]
    }
#undef ATTN_STAGE

    const size_t pbase = ((size_t)(ks * 16 + bh)) * SEQ;
    #pragma unroll
    for (int r = 0; r < 4; ++r) {
        float L = l_acc[r];
        #pragma unroll
        for (int msk = 1; msk < 16; msk <<= 1) L += __shfl_xor(L, msk);
        int qrow = qbase + quad * 4 + r;
        if (l16 == 0) Lpart[pbase + qrow] = L;
        #pragma unroll
        for (int dt = 0; dt < 4; ++dt)
            Opart[(pbase + qrow) * HEAD_DIM + dt * 16 + l16] = o[dt][r];
    }
}

// ---------------------------------------------------------------------------
// Combine 2 split-K attention partials: ctx = sum(O)/sum(l), bf16 [B,S,D].
// ---------------------------------------------------------------------------
__global__ __launch_bounds__(256) void attn_comb_k(
    const float* __restrict__ Op, const float* __restrict__ Lp,
    ushort_t* __restrict__ ctx)
{
    int g = blockIdx.x * 256 + threadIdx.x;      // 0..524287
    int d4 = g & 15;
    int q  = (g >> 4) & 2047;
    int bh = g >> 15;
    float ax = 0.f, ay = 0.f, az = 0.f, aw = 0.f, L = 0.f;
    #pragma unroll
    for (int ks = 0; ks < 2; ++ks) {
        size_t row = ((size_t)(ks * 16 + bh) * SEQ + q) * HEAD_DIM;
        float4 a = ((const float4*)(Op + row))[d4];
        ax += a.x; ay += a.y; az += a.z; aw += a.w;
        L += Lp[ks * 16 * SEQ + bh * SEQ + q];
    }
    float inv = 1.0f / L;
    ushort4 o4;
    o4.x = f2bf(ax * inv);
    o4.y = f2bf(ay * inv);
    o4.z = f2bf(az * inv);
    o4.w = f2bf(aw * inv);
    int bb = bh >> 3, hh = bh & 7;
    *(ushort4*)&ctx[((size_t)(bb * SEQ + q)) * D_MODEL + hh * HEAD_DIM + d4 * 4] = o4;
}

// ---------------------------------------------------------------------------
// Residual + LayerNorm over split-K partials:
// O[row] = LN(X + P0 + P1 + bias) * gamma + beta; optional bf16 copy.
// ---------------------------------------------------------------------------
template <int WRITE_BF>
__global__ __launch_bounds__(256) void add_ln_k(
    const float* __restrict__ X, const float* __restrict__ P0,
    const float* __restrict__ P1, const float* __restrict__ bias,
    const float* __restrict__ gam, const float* __restrict__ bet,
    float* __restrict__ O, ushort_t* __restrict__ Ob)
{
    const int row = blockIdx.x;
    const int t = threadIdx.x;
    const size_t ro = (size_t)row * D_MODEL;

    float v0 = X[ro + t]       + P0[ro + t]       + P1[ro + t]       + bias[t];
    float v1 = X[ro + t + 256] + P0[ro + t + 256] + P1[ro + t + 256] + bias[t + 256];
    float s = v0 + v1;
    float ss = v0 * v0 + v1 * v1;
    #pragma unroll
    for (int off = 32; off > 0; off >>= 1) {
        s  += __shfl_down(s, off);
        ss += __shfl_down(ss, off);
    }
    __shared__ float sb[4], ssb[4];
    if ((t & 63) == 0) { sb[t >> 6] = s; ssb[t >> 6] = ss; }
    __syncthreads();
    float S  = sb[0] + sb[1] + sb[2] + sb[3];
    float SS = ssb[0] + ssb[1] + ssb[2] + ssb[3];
    float mu  = S * (1.0f / D_MODEL);
    float var = SS * (1.0f / D_MODEL) - mu * mu;
    float inv = rsqrtf(var + 1e-5f);
    float o0 = (v0 - mu) * inv * gam[t] + bet[t];
    float o1 = (v1 - mu) * inv * gam[t + 256] + bet[t + 256];
    O[ro + t]       = o0;
    O[ro + t + 256] = o1;
    if (WRITE_BF) {
        Ob[ro + t]       = f2bf(o0);
        Ob[ro + t + 256] = f2bf(o1);
    }
}

// ---------------------------------------------------------------------------
extern "C" void kernel_launch(void* const* d_in, const int* in_sizes, int n_in,
                              void* d_out, int out_size, void* d_ws, size_t ws_size,
                              hipStream_t stream)
{
    const float* x   = (const float*)d_in[0];
    const float* Wq  = (const float*)d_in[1];
    const float* bq  = (const float*)d_in[2];
    const float* Wk  = (const float*)d_in[3];
    const float* bk  = (const float*)d_in[4];
    const float* Wv  = (const float*)d_in[5];
    const float* bv  = (const float*)d_in[6];
    const float* Wo  = (const float*)d_in[7];
    const float* bo  = (const float*)d_in[8];
    const float* W1  = (const float*)d_in[9];
    const float* b1  = (const float*)d_in[10];
    const float* W2  = (const float*)d_in[11];
    const float* b2  = (const float*)d_in[12];
    const float* g1  = (const float*)d_in[13];
    const float* be1 = (const float*)d_in[14];
    const float* g2  = (const float*)d_in[15];
    const float* be2 = (const float*)d_in[16];
    float* out = (float*)d_out;
    float* ws  = (float*)d_ws;

    // float-unit offsets; max end 13,172,736 fl = 52.7 MB (lifetime-overlaid)
    ushort_t* WoT   = (ushort_t*)(ws);               // [512][512] bf16
    ushort_t* W1T   = (ushort_t*)(ws + 131072);      // [2048][512]
    ushort_t* W2T   = (ushort_t*)(ws + 655360);      // [512][2048]
    ushort_t* WqkvT = (ushort_t*)(ws + 1179648);     // [1536][512]
    ushort_t* xb    = (ushort_t*)(ws + 1572864);     // [4096][512] bf16
    ushort_t* Qb    = (ushort_t*)(ws + 2621440);     // [16][2048][64]
    ushort_t* Kb    = (ushort_t*)(ws + 3670016);
    ushort_t* VTb   = (ushort_t*)(ws + 4718592);     // [16][64][2048]
    ushort_t* Ctx   = (ushort_t*)(ws + 5767168);     // [4096][512] bf16
    float*    Lpart = ws + 6815744;                  // [2][16][2048]
    float*    Hh    = ws + 6881280;                  // [4096][512] fp32
    float*    P0    = ws + 8978432;                  // [4096][512] fp32 partial
    float*    P1    = ws + 11075584;                 // [4096][512] fp32 partial
    float*    Opart = ws + 8978432;                  // [2][16][2048][64] (P0+P1 slot, dead before Wo)
    ushort_t* FF1   = (ushort_t*)(ws + 1572864);     // [4096][2048] bf16 (xb/Qb slot, dead by W1)
    ushort_t* Hhb   = (ushort_t*)(ws + 5767168);     // [4096][512] bf16 (Ctx slot, dead after Wo)

    // conversions (fused)
    prep_k<<<5120, 256, 0, stream>>>(x, Wq, Wk, Wv, Wo, W1, W2, xb, WqkvT, WoT, W1T, W2T);

    // QKV projection: BM=64, BK=128 swizzled core; 768 blocks
    gemm_qkv_k<<<dim3(12, 64), 256, 0, stream>>>(xb, WqkvT, bq, bk, bv, Qb, Kb, VTb);

    // flash attention v4 (async pipelined) split-K x2 -> partials -> combine
    attn_mfma_k<<<dim3(16, 32, 2), 256, 0, stream>>>(Qb, Kb, VTb, Opart, Lpart);
    attn_comb_k<<<2048, 256, 0, stream>>>(Opart, Lpart, Ctx);

    // output projection: split-K x2, raw fp32 partials (bias folded into LN1); 512 blocks
    gemm_std_k<2><<<dim3(4, 64, 2), 256, 0, stream>>>(
        Ctx, WoT, nullptr, P0, 512, 512, 256, (size_t)MROWS * D_MODEL);

    // h = LN(x + p0 + p1 + bo)
    add_ln_k<1><<<4096, 256, 0, stream>>>(x, P0, P1, bo, g1, be1, Hh, Hhb);

    // FFN up: bf16 + bias + ReLU; 1024 blocks
    gemm_std_k<1><<<dim3(16, 64), 256, 0, stream>>>(
        Hhb, W1T, b1, FF1, 2048, 512, 512, 0);

    // FFN down: split-K x2, raw fp32 partials (bias folded into LN2); 512 blocks
    gemm_std_k<2><<<dim3(4, 64, 2), 256, 0, stream>>>(
        FF1, W2T, nullptr, P0, 512, 2048, 1024, (size_t)MROWS * D_MODEL);

    // out = LN(h + q0 + q1 + b2)
    add_ln_k<0><<<4096, 256, 0, stream>>>(Hh, P0, P1, b2, g2, be2, out, (ushort_t*)nullptr);
}